// Round 3
// baseline (848.482 us; speedup 1.0000x reference)
//
#include <hip/hip_runtime.h>
#include <hip/hip_bf16.h>
#include <cstdint>
#include <cstddef>

using bf16 = __hip_bfloat16;
using short8 = __attribute__((ext_vector_type(8))) short;
using floatx4 = __attribute__((ext_vector_type(4))) float;

constexpr int D_IN = 1024;
constexpr int H_DIM = 4096;
constexpr int E_NUM = 8;
constexpr int NTOK = 8192;   // B*S
constexpr int NPAIR = NTOK * 2;

// ---------------- workspace layout (bytes) ----------------
constexpr size_t OFF_PTOK  = 1024;
constexpr size_t OFF_PPROB = 263168;
constexpr size_t OFF_SCHED = 525312;
constexpr size_t OFF_XBF   = 1048576;
constexpr size_t OFF_W2T   = OFF_XBF + (size_t)NTOK * D_IN * 2;
constexpr size_t OFF_HBUF  = OFF_W2T + (size_t)E_NUM * D_IN * H_DIM * 2;
constexpr size_t OFF_W1T   = OFF_HBUF + (size_t)NPAIR * H_DIM * 2;

__device__ __forceinline__ void cp16(const bf16* g, bf16* s) {
  __builtin_amdgcn_global_load_lds(
      (const __attribute__((address_space(1))) unsigned int*)g,
      (__attribute__((address_space(3))) unsigned int*)s, 16, 0, 0);
}

#define SCB() __builtin_amdgcn_sched_barrier(0)
#define BARRIER() { __builtin_amdgcn_s_barrier(); SCB(); }
#define LGKM0() { asm volatile("s_waitcnt lgkmcnt(0)" ::: "memory"); SCB(); }

// ---------- fp32 [K,N] -> bf16 [N,K] transposed convert, 64x64 tiles ----------
__global__ __launch_bounds__(256) void transpose_cvt(
    const float* __restrict__ in, bf16* __restrict__ out, int K, int N) {
  __shared__ float tile[64][65];
  const int e = blockIdx.z;
  const float* ip = in + (size_t)e * K * N + (size_t)(blockIdx.y * 64) * N + blockIdx.x * 64;
  bf16* op = out + (size_t)e * K * N + (size_t)(blockIdx.x * 64) * K + blockIdx.y * 64;
  const int tc = threadIdx.x & 15;   // col group (4 floats)
  const int tr = threadIdx.x >> 4;   // row 0..15
#pragma unroll
  for (int r = 0; r < 4; r++) {
    const float4 v = *(const float4*)&ip[(size_t)(tr + r * 16) * N + tc * 4];
    *(float4*)&tile[tr + r * 16][tc * 4] = v;
  }
  __syncthreads();
  const int kg = threadIdx.x & 7;    // k-group of 8
  const int nb = threadIdx.x >> 3;   // 0..31
#pragma unroll
  for (int r = 0; r < 2; r++) {
    const int n = nb + r * 32;
    union { short8 v; bf16 h[8]; } u;
#pragma unroll
    for (int j = 0; j < 8; j++) u.h[j] = __float2bfloat16(tile[kg * 8 + j][n]);
    *(short8*)&op[(size_t)n * K + kg * 8] = u.v;
  }
}

// ------- router: logits, softmax, top-2, x->bf16; hierarchical atomics ------
__global__ __launch_bounds__(256) void router_kernel(
    const float* __restrict__ x, const float* __restrict__ Wg,
    const float* __restrict__ bg, bf16* __restrict__ Xbf,
    int* __restrict__ counts, int* __restrict__ pairTok, float* __restrict__ pairProb) {
  __shared__ int lcnt[E_NUM];
  __shared__ int sBase[E_NUM];
  __shared__ int sE0[32], sL0[32], sE1[32], sL1[32];
  __shared__ float sP0[32], sP1[32];
  const int lane = threadIdx.x & 63;
  const int wave = threadIdx.x >> 6;
  if (threadIdx.x < E_NUM) lcnt[threadIdx.x] = 0;
  __syncthreads();

  for (int tk = 0; tk < 8; tk++) {
    const int li = wave * 8 + tk;
    const int n = blockIdx.x * 32 + li;
    const float* xr = x + (size_t)n * D_IN;
    bf16* xbr = Xbf + (size_t)n * D_IN;
    float logit[E_NUM];
#pragma unroll
    for (int e = 0; e < E_NUM; e++) logit[e] = 0.f;
#pragma unroll
    for (int i = 0; i < 16; i++) {
      const int d = i * 64 + lane;
      const float xd = xr[d];
      xbr[d] = __float2bfloat16(xd);
      const float4* wr = (const float4*)(Wg + (size_t)d * E_NUM);
      const float4 w0 = wr[0], w1 = wr[1];
      logit[0] += xd * w0.x; logit[1] += xd * w0.y;
      logit[2] += xd * w0.z; logit[3] += xd * w0.w;
      logit[4] += xd * w1.x; logit[5] += xd * w1.y;
      logit[6] += xd * w1.z; logit[7] += xd * w1.w;
    }
#pragma unroll
    for (int e = 0; e < E_NUM; e++) {
#pragma unroll
      for (int off = 32; off >= 1; off >>= 1)
        logit[e] += __shfl_xor(logit[e], off, 64);
    }
    if (lane == 0) {
      float l[E_NUM], mx = -1e30f;
#pragma unroll
      for (int e = 0; e < E_NUM; e++) { l[e] = logit[e] + bg[e]; mx = fmaxf(mx, l[e]); }
      float ex[E_NUM], s = 0.f;
#pragma unroll
      for (int e = 0; e < E_NUM; e++) { ex[e] = expf(l[e] - mx); s += ex[e]; }
      int i0 = 0;
#pragma unroll
      for (int e = 1; e < E_NUM; e++) if (l[e] > l[i0]) i0 = e;
      int i1 = (i0 == 0) ? 1 : 0;
#pragma unroll
      for (int e = 0; e < E_NUM; e++) if (e != i0 && l[e] > l[i1]) i1 = e;
      const float inv = 1.f / s;
      sE0[li] = i0; sL0[li] = atomicAdd(&lcnt[i0], 1); sP0[li] = ex[i0] * inv;
      sE1[li] = i1; sL1[li] = atomicAdd(&lcnt[i1], 1); sP1[li] = ex[i1] * inv;
    }
  }
  __syncthreads();
  if (threadIdx.x < E_NUM)
    sBase[threadIdx.x] = atomicAdd(&counts[threadIdx.x], lcnt[threadIdx.x]);
  __syncthreads();
  if (threadIdx.x < 32) {
    const int li = threadIdx.x;
    const int n = blockIdx.x * 32 + li;
    const int e0 = sE0[li], p0 = sBase[e0] + sL0[li];
    pairTok[e0 * NTOK + p0] = n;               // slot 0
    pairProb[e0 * NTOK + p0] = sP0[li];
    const int e1 = sE1[li], p1 = sBase[e1] + sL1[li];
    pairTok[e1 * NTOK + p1] = n | (1 << 15);   // slot 1
    pairProb[e1 * NTOK + p1] = sP1[li];
  }
}

// ------------- tile scheduler: exact (expert, m-tile[256]) list -------------
__global__ void sched_kernel(const int* __restrict__ counts, int* __restrict__ sched) {
  if (threadIdx.x == 0 && blockIdx.x == 0) {
    int* bases = sched;
    int* nTiles = sched + 8;
    int* tileMap = sched + 16;
    int base = 0, t = 0;
    for (int e = 0; e < E_NUM; e++) {
      bases[e] = base;
      const int nt = (counts[e] + 255) >> 8;   // 256-row tiles
      for (int m = 0; m < nt; m++) tileMap[t++] = (e << 16) | m;
      base += counts[e];
    }
    *nTiles = t;
  }
}

// ======== grouped GEMM, 256x256 tile, BK=64, 8 waves, 8-phase schedule ======
// Port of the verified 256^2 8-phase template (m201 lineage) to grouped MoE:
//  - 512 thr = 8 waves in 2M x 4N grid; per-wave output 128x64 (1/32 B/FLOP
//    vs 1/21 for the old 128^2/64x64 structure -> LDS-BW cap rises 40->61%).
//  - LDS 128 KB: 2 dbuf x (A 32KB + B 32KB) per K64-tile; 4 half-tiles/tile.
//  - Per K-tile 4 phases; each: [barrier] ds_read subtile {12,4,8,0} + stage
//    ONE half-tile (2x global_load_lds) -> lgkmcnt(0) -> setprio(1) 16 MFMA.
//    Quadrant rotation (0,0),(0,1),(1,1),(1,0); both B half-frag sets held.
//  - Counted vmcnt(2) ONCE per tile at P0 (retires this tile's 3 late halves,
//    keeps next tile's first half in flight -- never drains; T4).
//  - Half h0 of tile t+2 staged at P3 into the buffer being read (safe: all
//    waves' reads retired via their lgkmcnt(0) before the P3 barrier).
//  - Conflict-free LDS: 16B-chunk XOR swizzle c ^= (row&7); global_load_lds
//    dest stays LINEAR, the XOR is pre-applied to the per-lane GLOBAL source
//    chunk (involution) and to the ds_read address. 16-lane read groups then
//    hit 8 distinct 16B slots = 32 banks at 2 lanes/bank (free).
//  - Supertile XCD map (kept from round 2: FETCH 630->140 MB): 32 blocks
//    (= 32 CUs of one XCD at 1 block/CU) share 4mx8n (G1) / 8mx4n (G2).
// MODE 0: Hout[base+p][n] = gelu(Xbf[tok[p]] @ W1t[e]^T + b1[e])
// MODE 1: KS-split; atomicAdd(out[tok][n], (acc + (ks==0)*b2[e][n])*prob)
template <int MODE, int K, int NC, int KS>
__global__ __launch_bounds__(512, 2) void gemm8(
    const bf16* __restrict__ A, const bf16* __restrict__ Wt,
    const float* __restrict__ bias, const int* __restrict__ counts,
    const int* __restrict__ pairTok, const float* __restrict__ pairProb,
    const int* __restrict__ sched, bf16* __restrict__ Hout, float* __restrict__ out) {
  constexpr int KJOB = K / KS;
  constexpr int NT = KJOB / 64;

  __shared__ __align__(16) bf16 L[65536];   // 128 KB: [2 buf][A 16K elems | B 16K elems]

  const int xcd = blockIdx.x & 7;
  const int q = blockIdx.x >> 3;
  const int sg = q >> 5;
  const int j = q & 31;
  int mt, nb, ks = 0;
  if (MODE == 0) {
    const int st = xcd * 5 + sg;             // 36 real supertiles (18 ms x 2 ns)
    if (st >= 36) return;
    mt = (st >> 1) * 4 + (j >> 3);
    nb = (st & 1) * 8 + (j & 7);
  } else {
    const int st = xcd * 3 + sg;             // 18 real supertiles (2 ks x 9 ms)
    if (st >= 18) return;
    ks = st >= 9 ? 1 : 0;
    mt = (st - ks * 9) * 8 + (j >> 2);
    nb = j & 3;
  }
  if (mt >= sched[8]) return;
  const int ksOff = ks * KJOB;

  const int packed = sched[16 + mt];
  const int e = packed >> 16;
  const int m0 = (packed & 0xFFFF) * 256;
  const int cnt = counts[e];
  const int base = sched[e];
  const int n0 = nb * 256;

  const int tid = threadIdx.x;
  const int lane = tid & 63;
  const int wave = tid >> 6;
  const int wm = wave >> 2, wn = wave & 3;   // 2M x 4N wave grid, 128x64 each
  const int fr = lane & 15;
  const int g = lane >> 4;

  // ---- staging pointers (pre-swizzled source chunk: cg = (c ^ row&7)) ----
  const int r = tid >> 3;                    // 0..63
  const int cg8 = (((tid & 7) ^ (r & 7)) << 3);  // elems within a 64-elem row
  const bf16* aP[4];
  const bf16* bP[4];
#pragma unroll
  for (int i = 0; i < 4; i++) {
    const int rr = r + i * 64;               // rows r, r+64, r+128, r+192
    int p = m0 + rr; if (p > cnt - 1) p = cnt - 1;
    if (MODE == 0) {
      aP[i] = A + (size_t)(pairTok[e * NTOK + p] & 0x1FFF) * K + cg8;
    } else {
      aP[i] = A + (size_t)(base + p) * K + ksOff + cg8;
    }
    bP[i] = Wt + ((size_t)e * NC + n0 + rr) * K + ksOff + cg8;
  }

  // ---- ds_read offsets (elems), swizzled chunk c = (g + 4ks) ^ (lane&7) ----
  int aOff[2], bOff[2];
#pragma unroll
  for (int ksl = 0; ksl < 2; ksl++) {
    const int c = (g + ksl * 4) ^ (lane & 7);
    aOff[ksl] = (wm * 128 + fr) * 64 + c * 8;
    bOff[ksl] = 16384 + (wn * 64 + fr) * 64 + c * 8;
  }

  floatx4 acc[8][4];
#pragma unroll
  for (int mi = 0; mi < 8; mi++)
#pragma unroll
    for (int nf = 0; nf < 4; nf++) acc[mi][nf] = {0.f, 0.f, 0.f, 0.f};

  // stage half-tiles: A-half h -> buf + h*8192 (+4096 for row set1); B: +16384
  auto stageA = [&](int half, int t, int bufS) {
    const int kq = (t < NT ? t : NT - 1) * 64;
    cp16(aP[half * 2 + 0] + kq, &L[bufS + half * 8192 + tid * 8]);
    cp16(aP[half * 2 + 1] + kq, &L[bufS + half * 8192 + 4096 + tid * 8]);
  };
  auto stageB = [&](int half, int t, int bufS) {
    const int kq = (t < NT ? t : NT - 1) * 64;
    cp16(bP[half * 2 + 0] + kq, &L[bufS + 16384 + half * 8192 + tid * 8]);
    cp16(bP[half * 2 + 1] + kq, &L[bufS + 16384 + half * 8192 + 4096 + tid * 8]);
  };

  // prologue: tile0 all 4 halves + tile1 A-half0 (queue = 10 wave-loads)
  stageA(0, 0, 0); stageA(1, 0, 0); stageB(0, 0, 0); stageB(1, 0, 0);
  stageA(0, 1, 32768);

  short8 aR[4][2], bR[4][2];
  int bufR = 0;
#pragma unroll 1
  for (int t = 0; t < NT; ++t) {
    const int bufS = 32768 - bufR;           // buffer of tile t+1
    // ---------------- P0: Q(0,0) ----------------
    asm volatile("s_waitcnt vmcnt(2)" ::: "memory");  // tile t fully resident
    SCB();
    BARRIER();
#pragma unroll
    for (int ksl = 0; ksl < 2; ksl++) {
#pragma unroll
      for (int mf = 0; mf < 4; mf++)
        aR[mf][ksl] = *(const short8*)&L[bufR + aOff[ksl] + mf * 1024];
#pragma unroll
      for (int nf = 0; nf < 2; nf++)
        bR[nf][ksl] = *(const short8*)&L[bufR + bOff[ksl] + nf * 1024];
    }
    stageA(1, t + 1, bufS);
    LGKM0();
    __builtin_amdgcn_s_setprio(1);
#pragma unroll
    for (int ksl = 0; ksl < 2; ksl++)
#pragma unroll
      for (int mf = 0; mf < 4; mf++)
#pragma unroll
        for (int nf = 0; nf < 2; nf++)
          acc[mf][nf] = __builtin_amdgcn_mfma_f32_16x16x32_bf16(aR[mf][ksl], bR[nf][ksl], acc[mf][nf], 0, 0, 0);
    __builtin_amdgcn_s_setprio(0);
    // ---------------- P1: Q(0,1) ----------------
    BARRIER();
#pragma unroll
    for (int ksl = 0; ksl < 2; ksl++)
#pragma unroll
      for (int nf = 0; nf < 2; nf++)
        bR[2 + nf][ksl] = *(const short8*)&L[bufR + bOff[ksl] + (2 + nf) * 1024];
    stageB(0, t + 1, bufS);
    LGKM0();
    __builtin_amdgcn_s_setprio(1);
#pragma unroll
    for (int ksl = 0; ksl < 2; ksl++)
#pragma unroll
      for (int mf = 0; mf < 4; mf++)
#pragma unroll
        for (int nf = 0; nf < 2; nf++)
          acc[mf][2 + nf] = __builtin_amdgcn_mfma_f32_16x16x32_bf16(aR[mf][ksl], bR[2 + nf][ksl], acc[mf][2 + nf], 0, 0, 0);
    __builtin_amdgcn_s_setprio(0);
    // ---------------- P2: Q(1,1) ----------------
    BARRIER();
#pragma unroll
    for (int ksl = 0; ksl < 2; ksl++)
#pragma unroll
      for (int mf = 0; mf < 4; mf++)
        aR[mf][ksl] = *(const short8*)&L[bufR + aOff[ksl] + 4096 + mf * 1024];
    stageB(1, t + 1, bufS);
    LGKM0();
    __builtin_amdgcn_s_setprio(1);
#pragma unroll
    for (int ksl = 0; ksl < 2; ksl++)
#pragma unroll
      for (int mf = 0; mf < 4; mf++)
#pragma unroll
        for (int nf = 0; nf < 2; nf++)
          acc[4 + mf][2 + nf] = __builtin_amdgcn_mfma_f32_16x16x32_bf16(aR[mf][ksl], bR[2 + nf][ksl], acc[4 + mf][2 + nf], 0, 0, 0);
    __builtin_amdgcn_s_setprio(0);
    // ---------------- P3: Q(1,0) ----------------
    BARRIER();                               // all waves' P2 reads retired
    stageA(0, t + 2, bufR);                  // h0 of t+2 into buffer of t
    __builtin_amdgcn_s_setprio(1);
#pragma unroll
    for (int ksl = 0; ksl < 2; ksl++)
#pragma unroll
      for (int mf = 0; mf < 4; mf++)
#pragma unroll
        for (int nf = 0; nf < 2; nf++)
          acc[4 + mf][nf] = __builtin_amdgcn_mfma_f32_16x16x32_bf16(aR[mf][ksl], bR[nf][ksl], acc[4 + mf][nf], 0, 0, 0);
    __builtin_amdgcn_s_setprio(0);
    bufR = bufS;
  }
  asm volatile("s_waitcnt vmcnt(0)" ::: "memory");   // drain stage queue
  SCB();

  // ---------------- epilogue ----------------
  float bv[4];
#pragma unroll
  for (int nf = 0; nf < 4; nf++)
    bv[nf] = bias[(size_t)e * NC + n0 + wn * 64 + nf * 16 + fr];

#pragma unroll
  for (int mq = 0; mq < 2; mq++)
#pragma unroll
    for (int mf = 0; mf < 4; mf++) {
      const int rowb = m0 + wm * 128 + mq * 64 + mf * 16 + g * 4;
#pragma unroll
      for (int i = 0; i < 4; i++) {
        const int p = rowb + i;
        if (p < cnt) {
          if (MODE == 0) {
            bf16* orow = Hout + (size_t)(base + p) * NC + n0 + wn * 64 + fr;
#pragma unroll
            for (int nf = 0; nf < 4; nf++) {
              const float h = acc[mq * 4 + mf][nf][i] + bv[nf];
              const float gl = 0.5f * h * (1.f + erff(h * 0.70710678118f));
              orow[nf * 16] = __float2bfloat16(gl);
            }
          } else {
            const int pt = pairTok[e * NTOK + p];
            const float pr = pairProb[e * NTOK + p];
            const int tok = pt & 0x1FFF;
            float* orow = out + (size_t)tok * NC + n0 + wn * 64 + fr;
#pragma unroll
            for (int nf = 0; nf < 4; nf++) {
              float v = acc[mq * 4 + mf][nf][i];
              if (ks == 0) v += bv[nf];
              atomicAdd(&orow[nf * 16], v * pr);
            }
          }
        }
      }
    }
}

extern "C" void kernel_launch(void* const* d_in, const int* in_sizes, int n_in,
                              void* d_out, int out_size, void* d_ws, size_t ws_size,
                              hipStream_t stream) {
  const float* x  = (const float*)d_in[0];
  const float* Wg = (const float*)d_in[1];
  const float* bg = (const float*)d_in[2];
  const float* W1 = (const float*)d_in[3];
  const float* b1 = (const float*)d_in[4];
  const float* W2 = (const float*)d_in[5];
  const float* b2 = (const float*)d_in[6];
  float* out = (float*)d_out;
  char* ws = (char*)d_ws;

  int*   counts   = (int*)ws;
  int*   pairTok  = (int*)(ws + OFF_PTOK);
  float* pairProb = (float*)(ws + OFF_PPROB);
  int*   sched    = (int*)(ws + OFF_SCHED);
  bf16*  Xbf      = (bf16*)(ws + OFF_XBF);
  bf16*  W2t      = (bf16*)(ws + OFF_W2T);
  bf16*  Hbuf     = (bf16*)(ws + OFF_HBUF);
  bf16*  W1t      = (bf16*)(ws + OFF_W1T);

  hipMemsetAsync(counts, 0, 64, stream);
  hipMemsetAsync(out, 0, (size_t)NTOK * D_IN * sizeof(float), stream);
  // W1 [E][1024][4096] -> W1t [E][4096][1024]
  transpose_cvt<<<dim3(H_DIM / 64, D_IN / 64, E_NUM), 256, 0, stream>>>(W1, W1t, D_IN, H_DIM);
  // W2 [E][4096][1024] -> W2t [E][1024][4096]
  transpose_cvt<<<dim3(D_IN / 64, H_DIM / 64, E_NUM), 256, 0, stream>>>(W2, W2t, H_DIM, D_IN);
  router_kernel<<<NTOK / 32, 256, 0, stream>>>(x, Wg, bg, Xbf, counts, pairTok, pairProb);
  sched_kernel<<<1, 64, 0, stream>>>(counts, sched);
  // GEMM1: 8 XCDs x 5 supertile slots x 32 blocks = 1280 (36 real supertiles)
  gemm8<0, D_IN, H_DIM, 1><<<8 * 5 * 32, 512, 0, stream>>>(
      Xbf, W1t, b1, counts, pairTok, pairProb, sched, Hbuf, nullptr);
  // GEMM2: 8 XCDs x 3 supertile slots x 32 blocks = 768 (18 real supertiles)
  gemm8<1, H_DIM, D_IN, 2><<<8 * 3 * 32, 512, 0, stream>>>(
      Hbuf, W2t, b2, counts, pairTok, pairProb, sched, nullptr, out);
}